// Round 9
// baseline (764.304 us; speedup 1.0000x reference)
//
#include <hip/hip_runtime.h>
#include <cstdint>
#include <cmath>

#define DENSITY   0.05f
#define TOP_IG    7
#define NT        256
#define NT1       64
#define FEAT      4096
#define FEAT4     1024
#define NBIN1     2048     // 11-bit pass-1 digit
#define CAP1      1024     // candidate cap, kth target (typ ~220)
#define CAP0      512      // candidate cap, top_ig target (typ ~10)
#define CAPF      64       // finalist cap (typ ~2)

typedef float vfloat4 __attribute__((ext_vector_type(4)));

// monotonic float -> uint order key (ascending float == ascending key)
__device__ __forceinline__ unsigned fkey(float f) {
    unsigned u = __float_as_uint(f);
    return (u & 0x80000000u) ? ~u : (u | 0x80000000u);
}

// ---------------- kernel 1: chunked column partial sums (frozen) ----------------
__global__ __launch_bounds__(NT1)
void k_colsum_partial(const float4* __restrict__ x4, float4* __restrict__ part4,
                      int B, int F4v, int rowsPerChunk) {
    int cg = blockIdx.x * NT1 + threadIdx.x;
    if (cg >= F4v) return;
    int r0 = blockIdx.y * rowsPerChunk;
    int r1 = r0 + rowsPerChunk; if (r1 > B) r1 = B;
    float4 s0 = make_float4(0.f,0.f,0.f,0.f), s1 = s0, s2 = s0, s3 = s0;
    int r = r0;
    for (; r + 4 <= r1; r += 4) {
        float4 a = x4[(size_t)(r+0) * F4v + cg];
        float4 b = x4[(size_t)(r+1) * F4v + cg];
        float4 c = x4[(size_t)(r+2) * F4v + cg];
        float4 d = x4[(size_t)(r+3) * F4v + cg];
        s0.x += a.x; s0.y += a.y; s0.z += a.z; s0.w += a.w;
        s1.x += b.x; s1.y += b.y; s1.z += b.z; s1.w += b.w;
        s2.x += c.x; s2.y += c.y; s2.z += c.z; s2.w += c.w;
        s3.x += d.x; s3.y += d.y; s3.z += d.z; s3.w += d.w;
    }
    for (; r < r1; ++r) {
        float4 a = x4[(size_t)r * F4v + cg];
        s0.x += a.x; s0.y += a.y; s0.z += a.z; s0.w += a.w;
    }
    float4 s = make_float4(s0.x+s1.x+s2.x+s3.x, s0.y+s1.y+s2.y+s3.y,
                           s0.z+s1.z+s2.z+s3.z, s0.w+s1.w+s2.w+s3.w);
    part4[(size_t)blockIdx.y * F4v + cg] = s;
}

// ------------- kernel 2: reduce partials -> mean; compute factor (frozen) -------------
__global__ __launch_bounds__(NT)
void k_finalize_stats(const float4* __restrict__ part4, const float4* __restrict__ aa4,
                      float4* __restrict__ mean4, float4* __restrict__ factor4,
                      int B, int F4v, int nChunks) {
    __shared__ float4 red[4][64];
    int lane = threadIdx.x & 63;
    int q    = threadIdx.x >> 6;
    int cg   = blockIdx.x * 64 + lane;
    float4 s = make_float4(0.f, 0.f, 0.f, 0.f);
    if (cg < F4v) {
        for (int ch = q; ch < nChunks; ch += 4) {
            float4 v = part4[(size_t)ch * F4v + cg];
            s.x += v.x; s.y += v.y; s.z += v.z; s.w += v.w;
        }
    }
    red[q][lane] = s;
    __syncthreads();
    if (q == 0 && cg < F4v) {
        float4 a0 = red[0][lane], a1 = red[1][lane], a2 = red[2][lane], a3 = red[3][lane];
        float invB = 1.0f / (float)B;
        mean4[cg] = make_float4((a0.x + a1.x + a2.x + a3.x) * invB,
                                (a0.y + a1.y + a2.y + a3.y) * invB,
                                (a0.z + a1.z + a2.z + a3.z) * invB,
                                (a0.w + a1.w + a2.w + a3.w) * invB);
        float4 a = aa4[cg];
        factor4[cg] = make_float4((float)exp((double)(DENSITY - a.x)),
                                  (float)exp((double)(DENSITY - a.y)),
                                  (float)exp((double)(DENSITY - a.z)),
                                  (float)exp((double)(DENSITY - a.w)));
    }
}

// wave inclusive scan + total of per-lane value
__device__ __forceinline__ void wscan(unsigned T, int lane, unsigned& incl, unsigned& tot) {
    unsigned P = T;
    #pragma unroll
    for (int off = 1; off < 64; off <<= 1) {
        unsigned n = __shfl_up(P, off, 64);
        if (lane >= off) P += n;
    }
    incl = P;
    tot = __shfl(P, 63, 64);
}

// find rank rr_in in 256-bin histogram (lane owns 4 bins via uint4)
__device__ __forceinline__ void select256(const unsigned* h, int lane,
                                          unsigned rr_in, unsigned& sub, unsigned& rr) {
    uint4 c = *reinterpret_cast<const uint4*>(&h[lane << 2]);
    unsigned T = c.x + c.y + c.z + c.w;
    unsigned incl, tot; wscan(T, lane, incl, tot);
    unsigned above = tot - incl;
    bool hit = (above < rr_in) && (rr_in <= above + T);
    unsigned long long mk = __ballot(hit);
    int src = __ffsll(mk) - 1;
    unsigned aS = __shfl(above, src, 64);
    unsigned c0 = __shfl(c.x, src, 64), c1 = __shfl(c.y, src, 64);
    unsigned c2 = __shfl(c.z, src, 64), c3 = __shfl(c.w, src, 64);
    unsigned a3 = aS, a2 = a3 + c3, a1 = a2 + c2, a0 = a1 + c1;
    unsigned b, a;
    if      (a3 < rr_in && rr_in <= a3 + c3) { b = 3u; a = a3; }
    else if (a2 < rr_in && rr_in <= a2 + c2) { b = 2u; a = a2; }
    else if (a1 < rr_in && rr_in <= a1 + c1) { b = 1u; a = a1; }
    else                                     { b = 0u; a = a0; }
    sub = ((unsigned)src << 2) | b;
    rr  = rr_in - a;
}

// ------------- kernel 3: block-per-row, windowed dual select + compaction (frozen R8) -------------
__global__ __launch_bounds__(NT)
void k_select_apply(const float4* __restrict__ x4, const float4* __restrict__ factor4,
                    const float4* __restrict__ mean4, float4* __restrict__ out4,
                    int rankHi, int rankLo) {
    __shared__ __align__(16) unsigned hist1[NBIN1];
    __shared__ __align__(16) unsigned h8[2][256];
    __shared__ unsigned candS[CAP0];
    __shared__ unsigned candK[CAP1];
    __shared__ unsigned fin[2][CAPF];
    __shared__ unsigned cnts[4];
    __shared__ unsigned smax[4];
    __shared__ unsigned res[2];

    const int t    = threadIdx.x;
    const int wid  = t >> 6;
    const int lane = t & 63;
    const size_t rowBase = (size_t)blockIdx.x * FEAT4;

    #pragma unroll
    for (int i = 0; i < NBIN1 / NT; ++i) hist1[t + NT * i] = 0u;
    h8[0][t] = 0u; h8[1][t] = 0u;
    if (t < 4) cnts[t] = 0u;
    __syncthreads();                                   // B1

    unsigned kk[16];
    unsigned wm = 0u;
    #pragma unroll
    for (int jj = 0; jj < 4; ++jj) {
        int v = t + NT * jj;
        float4 X  = x4[rowBase + v];
        float4 Fa = factor4[v];
        unsigned k0 = fkey(X.x * Fa.x), k1 = fkey(X.y * Fa.y);
        unsigned k2 = fkey(X.z * Fa.z), k3 = fkey(X.w * Fa.w);
        kk[4*jj+0] = k0; kk[4*jj+1] = k1; kk[4*jj+2] = k2; kk[4*jj+3] = k3;
        wm = max(max(wm, max(k0, k1)), max(k2, k3));
        atomicAdd(&hist1[k0 >> 21], 1u);
        atomicAdd(&hist1[k1 >> 21], 1u);
        atomicAdd(&hist1[k2 >> 21], 1u);
        atomicAdd(&hist1[k3 >> 21], 1u);
    }
    #pragma unroll
    for (int off = 32; off > 0; off >>= 1)
        wm = max(wm, (unsigned)__shfl_xor(wm, off, 64));
    if (lane == 0) smax[wid] = wm;
    __syncthreads();                                   // B2

    unsigned bin0, rrem0 = (unsigned)rankHi;
    unsigned bin1, rrem1 = (unsigned)rankLo;
    {
        unsigned bm = max(max(smax[0], smax[1]), max(smax[2], smax[3]));
        int wstart = (int)(bm >> 21);
        bool f0 = false, f1 = false;
        unsigned base = 0u;
        while (!(f0 && f1)) {
            int b = wstart - lane;
            unsigned c = (b >= 0) ? hist1[b] : 0u;
            unsigned incl, tot; wscan(c, lane, incl, tot);
            unsigned above = base + incl - c;
            unsigned cum   = base + incl;
            if (!f0) {
                bool hit = (above < rrem0) && (rrem0 <= cum);
                unsigned long long mk = __ballot(hit);
                if (mk) { int s = __ffsll(mk) - 1; bin0 = (unsigned)(wstart - s);
                          rrem0 -= __shfl(above, s, 64); f0 = true; }
            }
            if (!f1) {
                bool hit = (above < rrem1) && (rrem1 <= cum);
                unsigned long long mk = __ballot(hit);
                if (mk) { int s = __ffsll(mk) - 1; bin1 = (unsigned)(wstart - s);
                          rrem1 -= __shfl(above, s, 64); f1 = true; }
            }
            base += tot;
            wstart -= 64;
        }
    }

    #pragma unroll
    for (int j = 0; j < 16; ++j) {
        unsigned k = kk[j];
        unsigned d = k >> 21;
        if (d == bin1) {
            unsigned idx = atomicAdd(&cnts[1], 1u);
            if (idx < CAP1) { candK[idx] = k; atomicAdd(&h8[1][(k >> 13) & 255u], 1u); }
        }
        if (d == bin0) {
            unsigned idx = atomicAdd(&cnts[0], 1u);
            if (idx < CAP0) { candS[idx] = k; atomicAdd(&h8[0][(k >> 13) & 255u], 1u); }
        }
    }
    __syncthreads();                                   // B3

    const int g = wid >> 1;
    unsigned subX, rrXf;
    select256(&h8[g][0], lane, (g == 0) ? rrem0 : rrem1, subX, rrXf);
    {
        unsigned binX = (g == 0) ? bin0 : bin1;
        unsigned preX = (binX << 8) | subX;
        unsigned Kc = cnts[g]; unsigned cap = (g == 0) ? CAP0 : CAP1; if (Kc > cap) Kc = cap;
        const unsigned* cand = (g == 0) ? candS : candK;
        for (unsigned i = (unsigned)(t & 127); i < Kc; i += 128) {
            unsigned k = cand[i];
            if ((k >> 13) == preX) {
                unsigned f = atomicAdd(&cnts[2 + g], 1u);
                if (f < CAPF) fin[g][f] = k;
            }
        }
    }
    __syncthreads();                                   // B4

    if ((wid & 1) == 0) {
        unsigned K = cnts[2 + g]; if (K > CAPF) K = CAPF;
        unsigned myk = fin[g][lane < (int)K ? lane : 0];
        unsigned gt = 0, eq = 0;
        for (unsigned i = 0; i < K; ++i) {
            unsigned v = fin[g][i];
            gt += (v > myk) ? 1u : 0u;
            eq += (v == myk) ? 1u : 0u;
        }
        bool hit = (lane < (int)K) && (gt < rrXf) && (rrXf <= gt + eq);
        unsigned long long mk = __ballot(hit);
        int src = __ffsll(mk) - 1;
        unsigned key = __shfl(myk, src, 64);
        if (lane == 0) res[g] = key;
    }
    __syncthreads();                                   // B5

    const unsigned keyHi = res[0];
    const unsigned keyLo = res[1];
    #pragma unroll
    for (int jj = 0; jj < 4; ++jj) {
        int v = t + NT * jj;
        float4 X = x4[rowBase + v];
        float4 M = mean4[v];
        unsigned k0 = kk[4*jj+0], k1 = kk[4*jj+1], k2 = kk[4*jj+2], k3 = kk[4*jj+3];
        vfloat4 o;
        o.x = (k0 <= keyHi) ? ((k0 >= keyLo) ? X.x - M.x : -M.x) : 0.0f;
        o.y = (k1 <= keyHi) ? ((k1 >= keyLo) ? X.y - M.y : -M.y) : 0.0f;
        o.z = (k2 <= keyHi) ? ((k2 >= keyLo) ? X.z - M.z : -M.z) : 0.0f;
        o.w = (k3 <= keyHi) ? ((k3 >= keyLo) ? X.w - M.w : -M.w) : 0.0f;
        __builtin_nontemporal_store(o, reinterpret_cast<vfloat4*>(&out4[rowBase + v]));
    }
}

// ================= DIAGNOSTIC ABLATION KERNELS (production d_out untouched) =================
// Rows rotate per iteration so global loads cannot be hoisted; checksums stored to d_ws.

// ---- phase A only: x-load + keygen + hist atomics + wave max ----
template<int ITERS>
__global__ __launch_bounds__(NT)
void k_abl_A(const float4* __restrict__ x4, const float4* __restrict__ factor4,
             unsigned* __restrict__ diag, int B) {
    __shared__ __align__(16) unsigned hist1[NBIN1];
    __shared__ unsigned smax[4];
    const int t    = threadIdx.x;
    const int wid  = t >> 6;
    const int lane = t & 63;
    unsigned acc = 0u;
    for (int it = 0; it < ITERS; ++it) {
        const size_t rowBase = (size_t)((blockIdx.x + it * 2749) & (B - 1)) * FEAT4;
        #pragma unroll
        for (int i = 0; i < NBIN1 / NT; ++i) hist1[t + NT * i] = 0u;
        __syncthreads();
        unsigned wm = 0u;
        #pragma unroll
        for (int jj = 0; jj < 4; ++jj) {
            int v = t + NT * jj;
            float4 X  = x4[rowBase + v];
            float4 Fa = factor4[v];
            unsigned k0 = fkey(X.x * Fa.x), k1 = fkey(X.y * Fa.y);
            unsigned k2 = fkey(X.z * Fa.z), k3 = fkey(X.w * Fa.w);
            wm = max(max(wm, max(k0, k1)), max(k2, k3));
            atomicAdd(&hist1[k0 >> 21], 1u);
            atomicAdd(&hist1[k1 >> 21], 1u);
            atomicAdd(&hist1[k2 >> 21], 1u);
            atomicAdd(&hist1[k3 >> 21], 1u);
        }
        #pragma unroll
        for (int off = 32; off > 0; off >>= 1)
            wm = max(wm, (unsigned)__shfl_xor(wm, off, 64));
        if (lane == 0) smax[wid] = wm;
        __syncthreads();
        acc ^= hist1[t] + hist1[t + 1024] + smax[wid];   // keep hist+max live
        __syncthreads();                                  // write-after-read guard
    }
    diag[(size_t)blockIdx.x * NT + t] = acc;
}

// ---- phases A..F: full dual select, no output pass ----
template<int ITERS>
__global__ __launch_bounds__(NT)
void k_abl_S(const float4* __restrict__ x4, const float4* __restrict__ factor4,
             unsigned* __restrict__ diag, int B, int rankHi, int rankLo) {
    __shared__ __align__(16) unsigned hist1[NBIN1];
    __shared__ __align__(16) unsigned h8[2][256];
    __shared__ unsigned candS[CAP0];
    __shared__ unsigned candK[CAP1];
    __shared__ unsigned fin[2][CAPF];
    __shared__ unsigned cnts[4];
    __shared__ unsigned smax[4];
    __shared__ unsigned res[2];

    const int t    = threadIdx.x;
    const int wid  = t >> 6;
    const int lane = t & 63;
    unsigned acc = 0u;

    for (int it = 0; it < ITERS; ++it) {
        const size_t rowBase = (size_t)((blockIdx.x + it * 5477) & (B - 1)) * FEAT4;
        #pragma unroll
        for (int i = 0; i < NBIN1 / NT; ++i) hist1[t + NT * i] = 0u;
        h8[0][t] = 0u; h8[1][t] = 0u;
        if (t < 4) cnts[t] = 0u;
        __syncthreads();                               // B1

        unsigned kk[16];
        unsigned wm = 0u;
        #pragma unroll
        for (int jj = 0; jj < 4; ++jj) {
            int v = t + NT * jj;
            float4 X  = x4[rowBase + v];
            float4 Fa = factor4[v];
            unsigned k0 = fkey(X.x * Fa.x), k1 = fkey(X.y * Fa.y);
            unsigned k2 = fkey(X.z * Fa.z), k3 = fkey(X.w * Fa.w);
            kk[4*jj+0] = k0; kk[4*jj+1] = k1; kk[4*jj+2] = k2; kk[4*jj+3] = k3;
            wm = max(max(wm, max(k0, k1)), max(k2, k3));
            atomicAdd(&hist1[k0 >> 21], 1u);
            atomicAdd(&hist1[k1 >> 21], 1u);
            atomicAdd(&hist1[k2 >> 21], 1u);
            atomicAdd(&hist1[k3 >> 21], 1u);
        }
        #pragma unroll
        for (int off = 32; off > 0; off >>= 1)
            wm = max(wm, (unsigned)__shfl_xor(wm, off, 64));
        if (lane == 0) smax[wid] = wm;
        __syncthreads();                               // B2

        unsigned bin0, rrem0 = (unsigned)rankHi;
        unsigned bin1, rrem1 = (unsigned)rankLo;
        {
            unsigned bm = max(max(smax[0], smax[1]), max(smax[2], smax[3]));
            int wstart = (int)(bm >> 21);
            bool f0 = false, f1 = false;
            unsigned base = 0u;
            while (!(f0 && f1)) {
                int b = wstart - lane;
                unsigned c = (b >= 0) ? hist1[b] : 0u;
                unsigned incl, tot; wscan(c, lane, incl, tot);
                unsigned above = base + incl - c;
                unsigned cum   = base + incl;
                if (!f0) {
                    bool hit = (above < rrem0) && (rrem0 <= cum);
                    unsigned long long mk = __ballot(hit);
                    if (mk) { int s = __ffsll(mk) - 1; bin0 = (unsigned)(wstart - s);
                              rrem0 -= __shfl(above, s, 64); f0 = true; }
                }
                if (!f1) {
                    bool hit = (above < rrem1) && (rrem1 <= cum);
                    unsigned long long mk = __ballot(hit);
                    if (mk) { int s = __ffsll(mk) - 1; bin1 = (unsigned)(wstart - s);
                              rrem1 -= __shfl(above, s, 64); f1 = true; }
                }
                base += tot;
                wstart -= 64;
            }
        }

        #pragma unroll
        for (int j = 0; j < 16; ++j) {
            unsigned k = kk[j];
            unsigned d = k >> 21;
            if (d == bin1) {
                unsigned idx = atomicAdd(&cnts[1], 1u);
                if (idx < CAP1) { candK[idx] = k; atomicAdd(&h8[1][(k >> 13) & 255u], 1u); }
            }
            if (d == bin0) {
                unsigned idx = atomicAdd(&cnts[0], 1u);
                if (idx < CAP0) { candS[idx] = k; atomicAdd(&h8[0][(k >> 13) & 255u], 1u); }
            }
        }
        __syncthreads();                               // B3

        const int g = wid >> 1;
        unsigned subX, rrXf;
        select256(&h8[g][0], lane, (g == 0) ? rrem0 : rrem1, subX, rrXf);
        {
            unsigned binX = (g == 0) ? bin0 : bin1;
            unsigned preX = (binX << 8) | subX;
            unsigned Kc = cnts[g]; unsigned cap = (g == 0) ? CAP0 : CAP1; if (Kc > cap) Kc = cap;
            const unsigned* cand = (g == 0) ? candS : candK;
            for (unsigned i = (unsigned)(t & 127); i < Kc; i += 128) {
                unsigned k = cand[i];
                if ((k >> 13) == preX) {
                    unsigned f = atomicAdd(&cnts[2 + g], 1u);
                    if (f < CAPF) fin[g][f] = k;
                }
            }
        }
        __syncthreads();                               // B4

        if ((wid & 1) == 0) {
            unsigned K = cnts[2 + g]; if (K > CAPF) K = CAPF;
            unsigned myk = fin[g][lane < (int)K ? lane : 0];
            unsigned gt = 0, eq = 0;
            for (unsigned i = 0; i < K; ++i) {
                unsigned v = fin[g][i];
                gt += (v > myk) ? 1u : 0u;
                eq += (v == myk) ? 1u : 0u;
            }
            bool hit = (lane < (int)K) && (gt < rrXf) && (rrXf <= gt + eq);
            unsigned long long mk = __ballot(hit);
            int src = __ffsll(mk) - 1;
            unsigned key = __shfl(myk, src, 64);
            if (lane == 0) res[g] = key;
        }
        __syncthreads();                               // B5
        acc ^= res[0] ^ res[1];
        __syncthreads();                               // guard before next-iter zero
    }
    diag[(size_t)blockIdx.x * NT + t] = acc;
}

extern "C" void kernel_launch(void* const* d_in, const int* in_sizes, int n_in,
                              void* d_out, int out_size, void* d_ws, size_t ws_size,
                              hipStream_t stream) {
    const float* x  = (const float*)d_in[0];
    const float* aa = (const float*)d_in[1];
    float* out = (float*)d_out;

    const int F   = in_sizes[1];          // 4096
    const int B   = in_sizes[0] / F;      // 8192
    const int F4v = F / 4;
    const int rankLo = (int)((double)F * 0.05) + TOP_IG;   // 211
    const int rankHi = TOP_IG;                              // 7

    int nChunks = 256;
    while (nChunks > 1 &&
           ((size_t)nChunks + 2) * (size_t)F * sizeof(float) > ws_size)
        nChunks >>= 1;
    if (nChunks > B) nChunks = B;

    float* part   = (float*)d_ws;
    float* mean   = part + (size_t)nChunks * F;
    float* factor = mean + F;
    int rpc = (B + nChunks - 1) / nChunks;

    dim3 g1((F4v + NT1 - 1) / NT1, nChunks);
    k_colsum_partial<<<g1, NT1, 0, stream>>>((const float4*)x, (float4*)part, B, F4v, rpc);

    k_finalize_stats<<<dim3((F4v + 63) / 64), NT, 0, stream>>>(
        (const float4*)part, (const float4*)aa, (float4*)mean, (float4*)factor, B, F4v, nChunks);

    k_select_apply<<<dim3(B), NT, 0, stream>>>(
        (const float4*)x, (const float4*)factor, (const float4*)mean, (float4*)out,
        rankHi, rankLo);

    // ---- diagnostics (after production output; write only to far d_ws regions) ----
    unsigned* diagA = (unsigned*)((char*)d_ws + (size_t)16 * 1024 * 1024);
    unsigned* diagS = (unsigned*)((char*)d_ws + (size_t)24 * 1024 * 1024);
    k_abl_A<16><<<dim3(B), NT, 0, stream>>>((const float4*)x, (const float4*)factor, diagA, B);
    k_abl_S<8><<<dim3(B), NT, 0, stream>>>((const float4*)x, (const float4*)factor, diagS, B,
                                           rankHi, rankLo);
}

// Round 10
// 154.873 us; speedup vs baseline: 4.9350x; 4.9350x over previous
//
#include <hip/hip_runtime.h>
#include <cstdint>
#include <cmath>

#define DENSITY   0.05f
#define TOP_IG    7
#define NT        256
#define NT1       64
#define FEAT      4096
#define FEAT4     1024
#define NBINS     1024     // 10-bit digit: key>>22 (sign+exp+1 mantissa bit)
#define TCAP1     768      // kth candidate cap (typ ~350-450 at half-octave bins)
#define TCAP0     128      // top_ig candidate cap (typ ~10)
#define TCAPF     32       // finalist cap (typ 1-3)
#define ROWS      4        // rows per k_apply block

typedef float vfloat4 __attribute__((ext_vector_type(4)));

// monotonic float -> uint order key (ascending float == ascending key)
__device__ __forceinline__ unsigned fkey(float f) {
    unsigned u = __float_as_uint(f);
    return (u & 0x80000000u) ? ~u : (u | 0x80000000u);
}

// ---------------- kernel 1: chunked column partial sums (frozen) ----------------
__global__ __launch_bounds__(NT1)
void k_colsum_partial(const float4* __restrict__ x4, float4* __restrict__ part4,
                      int B, int F4v, int rowsPerChunk) {
    int cg = blockIdx.x * NT1 + threadIdx.x;
    if (cg >= F4v) return;
    int r0 = blockIdx.y * rowsPerChunk;
    int r1 = r0 + rowsPerChunk; if (r1 > B) r1 = B;
    float4 s0 = make_float4(0.f,0.f,0.f,0.f), s1 = s0, s2 = s0, s3 = s0;
    int r = r0;
    for (; r + 4 <= r1; r += 4) {
        float4 a = x4[(size_t)(r+0) * F4v + cg];
        float4 b = x4[(size_t)(r+1) * F4v + cg];
        float4 c = x4[(size_t)(r+2) * F4v + cg];
        float4 d = x4[(size_t)(r+3) * F4v + cg];
        s0.x += a.x; s0.y += a.y; s0.z += a.z; s0.w += a.w;
        s1.x += b.x; s1.y += b.y; s1.z += b.z; s1.w += b.w;
        s2.x += c.x; s2.y += c.y; s2.z += c.z; s2.w += c.w;
        s3.x += d.x; s3.y += d.y; s3.z += d.z; s3.w += d.w;
    }
    for (; r < r1; ++r) {
        float4 a = x4[(size_t)r * F4v + cg];
        s0.x += a.x; s0.y += a.y; s0.z += a.z; s0.w += a.w;
    }
    float4 s = make_float4(s0.x+s1.x+s2.x+s3.x, s0.y+s1.y+s2.y+s3.y,
                           s0.z+s1.z+s2.z+s3.z, s0.w+s1.w+s2.w+s3.w);
    part4[(size_t)blockIdx.y * F4v + cg] = s;
}

// ------------- kernel 2: reduce partials -> mean; compute factor (frozen) -------------
__global__ __launch_bounds__(NT)
void k_finalize_stats(const float4* __restrict__ part4, const float4* __restrict__ aa4,
                      float4* __restrict__ mean4, float4* __restrict__ factor4,
                      int B, int F4v, int nChunks) {
    __shared__ float4 red[4][64];
    int lane = threadIdx.x & 63;
    int q    = threadIdx.x >> 6;
    int cg   = blockIdx.x * 64 + lane;
    float4 s = make_float4(0.f, 0.f, 0.f, 0.f);
    if (cg < F4v) {
        for (int ch = q; ch < nChunks; ch += 4) {
            float4 v = part4[(size_t)ch * F4v + cg];
            s.x += v.x; s.y += v.y; s.z += v.z; s.w += v.w;
        }
    }
    red[q][lane] = s;
    __syncthreads();
    if (q == 0 && cg < F4v) {
        float4 a0 = red[0][lane], a1 = red[1][lane], a2 = red[2][lane], a3 = red[3][lane];
        float invB = 1.0f / (float)B;
        mean4[cg] = make_float4((a0.x + a1.x + a2.x + a3.x) * invB,
                                (a0.y + a1.y + a2.y + a3.y) * invB,
                                (a0.z + a1.z + a2.z + a3.z) * invB,
                                (a0.w + a1.w + a2.w + a3.w) * invB);
        float4 a = aa4[cg];
        factor4[cg] = make_float4((float)exp((double)(DENSITY - a.x)),
                                  (float)exp((double)(DENSITY - a.y)),
                                  (float)exp((double)(DENSITY - a.z)),
                                  (float)exp((double)(DENSITY - a.w)));
    }
}

// wave inclusive scan + total of per-lane value
__device__ __forceinline__ void wscan(unsigned T, int lane, unsigned& incl, unsigned& tot) {
    unsigned P = T;
    #pragma unroll
    for (int off = 1; off < 64; off <<= 1) {
        unsigned n = __shfl_up(P, off, 64);
        if (lane >= off) P += n;
    }
    incl = P;
    tot = __shfl(P, 63, 64);
}

// find rank rr_in in a 256-bin histogram (lane owns 4 bins via uint4) — wave-level
__device__ __forceinline__ void select256(const unsigned* h, int lane,
                                          unsigned rr_in, unsigned& sub, unsigned& rr) {
    uint4 c = *reinterpret_cast<const uint4*>(&h[lane << 2]);
    unsigned T = c.x + c.y + c.z + c.w;
    unsigned incl, tot; wscan(T, lane, incl, tot);
    unsigned above = tot - incl;
    bool hit = (above < rr_in) && (rr_in <= above + T);
    unsigned long long mk = __ballot(hit);
    int src = __ffsll(mk) - 1;
    unsigned aS = __shfl(above, src, 64);
    unsigned c0 = __shfl(c.x, src, 64), c1 = __shfl(c.y, src, 64);
    unsigned c2 = __shfl(c.z, src, 64), c3 = __shfl(c.w, src, 64);
    unsigned a3 = aS, a2 = a3 + c3, a1 = a2 + c2, a0 = a1 + c1;
    unsigned b, a;
    if      (a3 < rr_in && rr_in <= a3 + c3) { b = 3u; a = a3; }
    else if (a2 < rr_in && rr_in <= a2 + c2) { b = 2u; a = a2; }
    else if (a1 < rr_in && rr_in <= a1 + c1) { b = 1u; a = a1; }
    else                                     { b = 0u; a = a0; }
    sub = ((unsigned)src << 2) | b;
    rr  = rr_in - a;
}

// ------------- kernel 3a: ONE WAVE PER ROW, zero barriers, dual threshold select -------------
// Wave-private LDS; in-order DS per wave guarantees zero->atomic->read sequencing.
__global__ __launch_bounds__(NT)
void k_thresholds(const float4* __restrict__ x4, const float4* __restrict__ factor4,
                  uint2* __restrict__ res2, int rankHi, int rankLo, int B) {
    __shared__ __align__(16) unsigned histS[4][NBINS];
    __shared__ __align__(16) unsigned h8S[4][2][256];
    __shared__ unsigned pool1S[4][TCAP1];
    __shared__ unsigned pool0S[4][TCAP0];
    __shared__ unsigned finS[4][2][TCAPF];
    __shared__ unsigned pcntS[4][4];   // [0]=cand0,[1]=cand1,[2]=fin0,[3]=fin1

    const int wid  = threadIdx.x >> 6;
    const int lane = threadIdx.x & 63;
    const int row  = blockIdx.x * 4 + wid;
    if (row >= B) return;

    unsigned* __restrict__ hist  = histS[wid];
    unsigned* __restrict__ h80   = h8S[wid][0];
    unsigned* __restrict__ h81   = h8S[wid][1];
    unsigned* __restrict__ pool0 = pool0S[wid];
    unsigned* __restrict__ pool1 = pool1S[wid];
    unsigned* __restrict__ fin0  = finS[wid][0];
    unsigned* __restrict__ fin1  = finS[wid][1];
    unsigned* __restrict__ pcnt  = pcntS[wid];

    // ---- zero wave-private LDS (b128 writes) ----
    {
        uint4 z = make_uint4(0u,0u,0u,0u);
        #pragma unroll
        for (int i = 0; i < 4; ++i)
            *reinterpret_cast<uint4*>(&hist[4 * (lane + 64 * i)]) = z;
        *reinterpret_cast<uint4*>(&h80[4 * lane]) = z;
        *reinterpret_cast<uint4*>(&h81[4 * lane]) = z;
        if (lane < 4) pcnt[lane] = 0u;
    }

    const float4* __restrict__ row4 = x4 + (size_t)row * FEAT4;

    // ---- pass 1: keygen + 10-bit histogram + wave max (keys not kept: 64/lane would spill) ----
    unsigned wm = 0u;
    #pragma unroll
    for (int j = 0; j < 16; ++j) {
        int v = lane + 64 * j;
        float4 X  = row4[v];
        float4 Fa = factor4[v];
        unsigned k0 = fkey(X.x * Fa.x), k1 = fkey(X.y * Fa.y);
        unsigned k2 = fkey(X.z * Fa.z), k3 = fkey(X.w * Fa.w);
        wm = max(max(max(wm, k0), max(k1, k2)), k3);
        atomicAdd(&hist[k0 >> 22], 1u);
        atomicAdd(&hist[k1 >> 22], 1u);
        atomicAdd(&hist[k2 >> 22], 1u);
        atomicAdd(&hist[k3 >> 22], 1u);
    }
    #pragma unroll
    for (int off = 32; off > 0; off >>= 1)
        wm = max(wm, (unsigned)__shfl_xor(wm, off, 64));

    // ---- windowed suffix scan from the top bin: resolves BOTH ranks, wave-level ----
    unsigned bin0 = 0, rr0 = (unsigned)rankHi;   // rank 7 (top_ig)
    unsigned bin1 = 0, rr1 = (unsigned)rankLo;   // rank 211 (kth)
    {
        int wstart = (int)(wm >> 22);
        bool f0 = false, f1 = false;
        unsigned base = 0u;
        while (!(f0 && f1)) {
            int b = wstart - lane;
            unsigned c = (b >= 0) ? hist[b] : 0u;
            unsigned incl, tot; wscan(c, lane, incl, tot);
            unsigned above = base + incl - c;
            unsigned cum   = base + incl;
            if (!f0) {
                bool hit = (above < rr0) && (rr0 <= cum);
                unsigned long long mk = __ballot(hit);
                if (mk) { int s = __ffsll(mk) - 1; bin0 = (unsigned)(wstart - s);
                          rr0 -= __shfl(above, s, 64); f0 = true; }
            }
            if (!f1) {
                bool hit = (above < rr1) && (rr1 <= cum);
                unsigned long long mk = __ballot(hit);
                if (mk) { int s = __ffsll(mk) - 1; bin1 = (unsigned)(wstart - s);
                          rr1 -= __shfl(above, s, 64); f1 = true; }
            }
            base += tot;
            wstart -= 64;
        }
    }

    // ---- pass 2: recompute keys (row is L1/L2-hot), compact candidates + 8-bit sub-hists ----
    #pragma unroll
    for (int j = 0; j < 16; ++j) {
        int v = lane + 64 * j;
        float4 X  = row4[v];
        float4 Fa = factor4[v];
        unsigned ks0 = fkey(X.x * Fa.x), ks1 = fkey(X.y * Fa.y);
        unsigned ks2 = fkey(X.z * Fa.z), ks3 = fkey(X.w * Fa.w);
        #pragma unroll
        for (int e = 0; e < 4; ++e) {
            unsigned k = (e == 0) ? ks0 : (e == 1) ? ks1 : (e == 2) ? ks2 : ks3;
            unsigned d = k >> 22;
            if (d == bin1) {
                unsigned pos = atomicAdd(&pcnt[1], 1u);
                if (pos < TCAP1) pool1[pos] = k;
                atomicAdd(&h81[(k >> 14) & 255u], 1u);
            }
            if (d == bin0) {
                unsigned pos = atomicAdd(&pcnt[0], 1u);
                if (pos < TCAP0) pool0[pos] = k;
                atomicAdd(&h80[(k >> 14) & 255u], 1u);
            }
        }
    }
    unsigned cnt0 = pcnt[0]; if (cnt0 > TCAP0) cnt0 = TCAP0;
    unsigned cnt1 = pcnt[1]; if (cnt1 > TCAP1) cnt1 = TCAP1;

    // ---- 8-bit sub-digit select for both targets (wave-level) ----
    unsigned sub0, rrf0; select256(h80, lane, rr0, sub0, rrf0);
    unsigned sub1, rrf1; select256(h81, lane, rr1, sub1, rrf1);

    // ---- gather finalists (18-bit prefix match) ----
    unsigned pre0 = (bin0 << 8) | sub0;
    unsigned pre1 = (bin1 << 8) | sub1;
    for (unsigned i = lane; i < cnt1; i += 64) {
        unsigned k = pool1[i];
        if ((k >> 14) == pre1) { unsigned f = atomicAdd(&pcnt[3], 1u); if (f < TCAPF) fin1[f] = k; }
    }
    for (unsigned i = lane; i < cnt0; i += 64) {
        unsigned k = pool0[i];
        if ((k >> 14) == pre0) { unsigned f = atomicAdd(&pcnt[2], 1u); if (f < TCAPF) fin0[f] = k; }
    }

    // ---- exact rank by duplicate-aware counting ----
    unsigned keyHi, keyLo;
    {
        unsigned K = pcnt[2]; if (K > TCAPF) K = TCAPF;
        unsigned myk = fin0[lane < (int)K ? lane : 0];
        unsigned gt = 0, eq = 0;
        for (unsigned i = 0; i < K; ++i) {
            unsigned vv = fin0[i];
            gt += (vv > myk) ? 1u : 0u;
            eq += (vv == myk) ? 1u : 0u;
        }
        bool hit = (lane < (int)K) && (gt < rrf0) && (rrf0 <= gt + eq);
        unsigned long long mk = __ballot(hit);
        int s = __ffsll(mk) - 1;
        keyHi = __shfl(myk, s, 64);
    }
    {
        unsigned K = pcnt[3]; if (K > TCAPF) K = TCAPF;
        unsigned myk = fin1[lane < (int)K ? lane : 0];
        unsigned gt = 0, eq = 0;
        for (unsigned i = 0; i < K; ++i) {
            unsigned vv = fin1[i];
            gt += (vv > myk) ? 1u : 0u;
            eq += (vv == myk) ? 1u : 0u;
        }
        bool hit = (lane < (int)K) && (gt < rrf1) && (rrf1 <= gt + eq);
        unsigned long long mk = __ballot(hit);
        int s = __ffsll(mk) - 1;
        keyLo = __shfl(myk, s, 64);
    }
    if (lane == 0) res2[row] = make_uint2(keyHi, keyLo);
}

// ------------- kernel 3b: streaming apply (no LDS, no barriers) -------------
__device__ __forceinline__ void apply_chunk(float4 X, float4 Fa, float4 M, uint2 th,
                                            float4* __restrict__ dst) {
    unsigned k0 = fkey(X.x * Fa.x), k1 = fkey(X.y * Fa.y);
    unsigned k2 = fkey(X.z * Fa.z), k3 = fkey(X.w * Fa.w);
    vfloat4 o;
    o.x = (k0 <= th.x) ? ((k0 >= th.y) ? X.x - M.x : -M.x) : 0.0f;
    o.y = (k1 <= th.x) ? ((k1 >= th.y) ? X.y - M.y : -M.y) : 0.0f;
    o.z = (k2 <= th.x) ? ((k2 >= th.y) ? X.z - M.z : -M.z) : 0.0f;
    o.w = (k3 <= th.x) ? ((k3 >= th.y) ? X.w - M.w : -M.w) : 0.0f;
    __builtin_nontemporal_store(o, reinterpret_cast<vfloat4*>(dst));
}

__global__ __launch_bounds__(NT)
void k_apply(const float4* __restrict__ x4, const float4* __restrict__ factor4,
             const float4* __restrict__ mean4, const uint2* __restrict__ res2,
             float4* __restrict__ out4, int B) {
    const int t = threadIdx.x;
    float4 Fa0 = factor4[t],       Fa1 = factor4[t + 256];
    float4 Fa2 = factor4[t + 512], Fa3 = factor4[t + 768];
    float4 M0  = mean4[t],         M1  = mean4[t + 256];
    float4 M2  = mean4[t + 512],   M3  = mean4[t + 768];
    int r0 = blockIdx.x * ROWS;
    #pragma unroll
    for (int rr = 0; rr < ROWS; ++rr) {
        int r = r0 + rr;
        if (r >= B) break;
        uint2 th = res2[r];
        const float4* __restrict__ row  = x4   + (size_t)r * FEAT4;
        float4* __restrict__       orow = out4 + (size_t)r * FEAT4;
        apply_chunk(row[t],       Fa0, M0, th, &orow[t]);
        apply_chunk(row[t + 256], Fa1, M1, th, &orow[t + 256]);
        apply_chunk(row[t + 512], Fa2, M2, th, &orow[t + 512]);
        apply_chunk(row[t + 768], Fa3, M3, th, &orow[t + 768]);
    }
}

extern "C" void kernel_launch(void* const* d_in, const int* in_sizes, int n_in,
                              void* d_out, int out_size, void* d_ws, size_t ws_size,
                              hipStream_t stream) {
    const float* x  = (const float*)d_in[0];
    const float* aa = (const float*)d_in[1];
    float* out = (float*)d_out;

    const int F   = in_sizes[1];          // 4096
    const int B   = in_sizes[0] / F;      // 8192
    const int F4v = F / 4;
    const int rankLo = (int)((double)F * 0.05) + TOP_IG;   // 211
    const int rankHi = TOP_IG;                              // 7

    int nChunks = 256;
    while (nChunks > 1 &&
           ((size_t)nChunks + 2) * (size_t)F * sizeof(float) + 8 * (size_t)B > ws_size)
        nChunks >>= 1;
    if (nChunks > B) nChunks = B;

    float* part   = (float*)d_ws;
    float* mean   = part + (size_t)nChunks * F;
    float* factor = mean + F;
    uint2* res2   = (uint2*)(factor + F);
    int rpc = (B + nChunks - 1) / nChunks;

    dim3 g1((F4v + NT1 - 1) / NT1, nChunks);
    k_colsum_partial<<<g1, NT1, 0, stream>>>((const float4*)x, (float4*)part, B, F4v, rpc);

    k_finalize_stats<<<dim3((F4v + 63) / 64), NT, 0, stream>>>(
        (const float4*)part, (const float4*)aa, (float4*)mean, (float4*)factor, B, F4v, nChunks);

    k_thresholds<<<dim3((B + 3) / 4), NT, 0, stream>>>(
        (const float4*)x, (const float4*)factor, res2, rankHi, rankLo, B);

    k_apply<<<dim3((B + ROWS - 1) / ROWS), NT, 0, stream>>>(
        (const float4*)x, (const float4*)factor, (const float4*)mean, res2,
        (float4*)out, B);
}

// Round 11
// 109.681 us; speedup vs baseline: 6.9684x; 1.4120x over previous
//
#include <hip/hip_runtime.h>
#include <cstdint>
#include <cmath>

#define DENSITY   0.05f
#define TOP_IG    7
#define NT        256
#define NT1       64
#define FEAT      4096
#define FEAT4     1024
#define NBINS     1024     // 10-bit pass-1 digit: key>>22 (sign+exp+1 mantissa bit)
#define CAPF      32       // finalist cap (typ 1-3)

typedef float vfloat4 __attribute__((ext_vector_type(4)));

// monotonic float -> uint order key (ascending float == ascending key)
__device__ __forceinline__ unsigned fkey(float f) {
    unsigned u = __float_as_uint(f);
    return (u & 0x80000000u) ? ~u : (u | 0x80000000u);
}

// ---------------- kernel 1: chunked column partial sums (frozen) ----------------
__global__ __launch_bounds__(NT1)
void k_colsum_partial(const float4* __restrict__ x4, float4* __restrict__ part4,
                      int B, int F4v, int rowsPerChunk) {
    int cg = blockIdx.x * NT1 + threadIdx.x;
    if (cg >= F4v) return;
    int r0 = blockIdx.y * rowsPerChunk;
    int r1 = r0 + rowsPerChunk; if (r1 > B) r1 = B;
    float4 s0 = make_float4(0.f,0.f,0.f,0.f), s1 = s0, s2 = s0, s3 = s0;
    int r = r0;
    for (; r + 4 <= r1; r += 4) {
        float4 a = x4[(size_t)(r+0) * F4v + cg];
        float4 b = x4[(size_t)(r+1) * F4v + cg];
        float4 c = x4[(size_t)(r+2) * F4v + cg];
        float4 d = x4[(size_t)(r+3) * F4v + cg];
        s0.x += a.x; s0.y += a.y; s0.z += a.z; s0.w += a.w;
        s1.x += b.x; s1.y += b.y; s1.z += b.z; s1.w += b.w;
        s2.x += c.x; s2.y += c.y; s2.z += c.z; s2.w += c.w;
        s3.x += d.x; s3.y += d.y; s3.z += d.z; s3.w += d.w;
    }
    for (; r < r1; ++r) {
        float4 a = x4[(size_t)r * F4v + cg];
        s0.x += a.x; s0.y += a.y; s0.z += a.z; s0.w += a.w;
    }
    float4 s = make_float4(s0.x+s1.x+s2.x+s3.x, s0.y+s1.y+s2.y+s3.y,
                           s0.z+s1.z+s2.z+s3.z, s0.w+s1.w+s2.w+s3.w);
    part4[(size_t)blockIdx.y * F4v + cg] = s;
}

// ------------- kernel 2: reduce partials -> mean; compute factor (frozen) -------------
__global__ __launch_bounds__(NT)
void k_finalize_stats(const float4* __restrict__ part4, const float4* __restrict__ aa4,
                      float4* __restrict__ mean4, float4* __restrict__ factor4,
                      int B, int F4v, int nChunks) {
    __shared__ float4 red[4][64];
    int lane = threadIdx.x & 63;
    int q    = threadIdx.x >> 6;
    int cg   = blockIdx.x * 64 + lane;
    float4 s = make_float4(0.f, 0.f, 0.f, 0.f);
    if (cg < F4v) {
        for (int ch = q; ch < nChunks; ch += 4) {
            float4 v = part4[(size_t)ch * F4v + cg];
            s.x += v.x; s.y += v.y; s.z += v.z; s.w += v.w;
        }
    }
    red[q][lane] = s;
    __syncthreads();
    if (q == 0 && cg < F4v) {
        float4 a0 = red[0][lane], a1 = red[1][lane], a2 = red[2][lane], a3 = red[3][lane];
        float invB = 1.0f / (float)B;
        mean4[cg] = make_float4((a0.x + a1.x + a2.x + a3.x) * invB,
                                (a0.y + a1.y + a2.y + a3.y) * invB,
                                (a0.z + a1.z + a2.z + a3.z) * invB,
                                (a0.w + a1.w + a2.w + a3.w) * invB);
        float4 a = aa4[cg];
        factor4[cg] = make_float4((float)exp((double)(DENSITY - a.x)),
                                  (float)exp((double)(DENSITY - a.y)),
                                  (float)exp((double)(DENSITY - a.z)),
                                  (float)exp((double)(DENSITY - a.w)));
    }
}

// wave inclusive scan + total of per-lane value
__device__ __forceinline__ void wscan(unsigned T, int lane, unsigned& incl, unsigned& tot) {
    unsigned P = T;
    #pragma unroll
    for (int off = 1; off < 64; off <<= 1) {
        unsigned n = __shfl_up(P, off, 64);
        if (lane >= off) P += n;
    }
    incl = P;
    tot = __shfl(P, 63, 64);
}

// find rank rr_in in a 256-bin histogram (lane owns 4 bins via uint4) — wave-level
__device__ __forceinline__ void select256(const unsigned* h, int lane,
                                          unsigned rr_in, unsigned& sub, unsigned& rr) {
    uint4 c = *reinterpret_cast<const uint4*>(&h[lane << 2]);
    unsigned T = c.x + c.y + c.z + c.w;
    unsigned incl, tot; wscan(T, lane, incl, tot);
    unsigned above = tot - incl;
    bool hit = (above < rr_in) && (rr_in <= above + T);
    unsigned long long mk = __ballot(hit);
    int src = __ffsll(mk) - 1;
    unsigned aS = __shfl(above, src, 64);
    unsigned c0 = __shfl(c.x, src, 64), c1 = __shfl(c.y, src, 64);
    unsigned c2 = __shfl(c.z, src, 64), c3 = __shfl(c.w, src, 64);
    unsigned a3 = aS, a2 = a3 + c3, a1 = a2 + c2, a0 = a1 + c1;
    unsigned b, a;
    if      (a3 < rr_in && rr_in <= a3 + c3) { b = 3u; a = a3; }
    else if (a2 < rr_in && rr_in <= a2 + c2) { b = 2u; a = a2; }
    else if (a1 < rr_in && rr_in <= a1 + c1) { b = 1u; a = a1; }
    else                                     { b = 0u; a = a0; }
    sub = ((unsigned)src << 2) | b;
    rr  = rr_in - a;
}

// duplicate-aware rank resolve among finalists (wave-level, redundant per wave)
__device__ __forceinline__ unsigned resolve_fin(const unsigned* fin, unsigned K,
                                                unsigned rr, int lane) {
    unsigned myk = fin[lane < (int)K ? lane : 0];
    unsigned gt = 0, eq = 0;
    for (unsigned i = 0; i < K; ++i) {
        unsigned v = fin[i];                 // LDS broadcast
        gt += (v > myk) ? 1u : 0u;
        eq += (v == myk) ? 1u : 0u;
    }
    bool hit = (lane < (int)K) && (gt < rr) && (rr <= gt + eq);
    unsigned long long mk = __ballot(hit);
    if (mk == 0ull) return fin[0];           // cap-overflow fallback (ties beyond CAPF)
    int src = __ffsll(mk) - 1;
    return __shfl(myk, src, 64);
}

// ------------- kernel 3: block-per-row dual select (lean LDS, 4 barriers) -------------
__global__ __launch_bounds__(NT)
void k_select_apply(const float4* __restrict__ x4, const float4* __restrict__ factor4,
                    const float4* __restrict__ mean4, float4* __restrict__ out4,
                    int rankHi, int rankLo) {
    __shared__ __align__(16) unsigned hist[NBINS];   // 4 KB
    __shared__ __align__(16) unsigned h8[2][256];    // 2 KB
    __shared__ unsigned fin[2][CAPF];                // 256 B
    __shared__ unsigned fcnt[2];
    __shared__ unsigned smax[4];

    const int t    = threadIdx.x;
    const int wid  = t >> 6;
    const int lane = t & 63;
    const size_t rowBase = (size_t)blockIdx.x * FEAT4;

    // ---- zero ----
    *reinterpret_cast<uint4*>(&hist[4 * t]) = make_uint4(0u,0u,0u,0u);
    h8[0][t] = 0u; h8[1][t] = 0u;
    if (t < 2) fcnt[t] = 0u;
    __syncthreads();                                   // B1

    // ---- phase A: keygen (keys stay in VGPRs) + 10-bit histogram + wave max ----
    unsigned kk[16];
    unsigned wm = 0u;
    #pragma unroll
    for (int jj = 0; jj < 4; ++jj) {
        int v = t + NT * jj;
        float4 X  = x4[rowBase + v];
        float4 Fa = factor4[v];
        unsigned k0 = fkey(X.x * Fa.x), k1 = fkey(X.y * Fa.y);
        unsigned k2 = fkey(X.z * Fa.z), k3 = fkey(X.w * Fa.w);
        kk[4*jj+0] = k0; kk[4*jj+1] = k1; kk[4*jj+2] = k2; kk[4*jj+3] = k3;
        wm = max(max(max(wm, k0), max(k1, k2)), k3);
        atomicAdd(&hist[k0 >> 22], 1u);
        atomicAdd(&hist[k1 >> 22], 1u);
        atomicAdd(&hist[k2 >> 22], 1u);
        atomicAdd(&hist[k3 >> 22], 1u);
    }
    #pragma unroll
    for (int off = 32; off > 0; off >>= 1)
        wm = max(wm, (unsigned)__shfl_xor(wm, off, 64));
    if (lane == 0) smax[wid] = wm;
    __syncthreads();                                   // B2

    // ---- phase B: windowed suffix scan from the top bin (redundant per wave) ----
    unsigned bin0 = 0, rr0 = (unsigned)rankHi;         // rank 7 (top_ig)
    unsigned bin1 = 0, rr1 = (unsigned)rankLo;         // rank 211 (kth)
    {
        unsigned bm = max(max(smax[0], smax[1]), max(smax[2], smax[3]));
        int wstart = (int)(bm >> 22);
        bool f0 = false, f1 = false;
        unsigned base = 0u;
        while (!(f0 && f1)) {
            int b = wstart - lane;
            unsigned c = (b >= 0) ? hist[b] : 0u;
            unsigned incl, tot; wscan(c, lane, incl, tot);
            unsigned above = base + incl - c;
            unsigned cum   = base + incl;
            if (!f0) {
                bool hit = (above < rr0) && (rr0 <= cum);
                unsigned long long mk = __ballot(hit);
                if (mk) { int s = __ffsll(mk) - 1; bin0 = (unsigned)(wstart - s);
                          rr0 -= __shfl(above, s, 64); f0 = true; }
            }
            if (!f1) {
                bool hit = (above < rr1) && (rr1 <= cum);
                unsigned long long mk = __ballot(hit);
                if (mk) { int s = __ffsll(mk) - 1; bin1 = (unsigned)(wstart - s);
                          rr1 -= __shfl(above, s, 64); f1 = true; }
            }
            base += tot;
            wstart -= 64;
        }
    }

    // ---- phase C: 8-bit sub-histograms for both target bins (no pools) ----
    #pragma unroll
    for (int j = 0; j < 16; ++j) {
        unsigned k = kk[j];
        unsigned d = k >> 22;
        if (d == bin1) atomicAdd(&h8[1][(k >> 14) & 255u], 1u);
        if (d == bin0) atomicAdd(&h8[0][(k >> 14) & 255u], 1u);
    }
    __syncthreads();                                   // B3

    // ---- phase D: sub-digit select, both targets, redundant per wave ----
    unsigned sub0, rrf0; select256(&h8[0][0], lane, rr0, sub0, rrf0);
    unsigned sub1, rrf1; select256(&h8[1][0], lane, rr1, sub1, rrf1);

    // ---- phase E: finalist gather by re-scanning register keys (18-bit prefix) ----
    {
        unsigned pre0 = (bin0 << 8) | sub0;
        unsigned pre1 = (bin1 << 8) | sub1;
        #pragma unroll
        for (int j = 0; j < 16; ++j) {
            unsigned k = kk[j];
            unsigned p = k >> 14;
            if (p == pre1) { unsigned f = atomicAdd(&fcnt[1], 1u); if (f < CAPF) fin[1][f] = k; }
            if (p == pre0) { unsigned f = atomicAdd(&fcnt[0], 1u); if (f < CAPF) fin[0][f] = k; }
        }
    }
    __syncthreads();                                   // B4

    // ---- phase F: exact rank among finalists, redundant per wave (no more barriers) ----
    unsigned K0 = fcnt[0]; if (K0 > CAPF) K0 = CAPF;
    unsigned K1 = fcnt[1]; if (K1 > CAPF) K1 = CAPF;
    const unsigned keyHi = resolve_fin(&fin[0][0], K0, rrf0, lane);
    const unsigned keyLo = resolve_fin(&fin[1][0], K1, rrf1, lane);

    // ---- phase G: apply masks (x re-read: L2-hot) ----
    #pragma unroll
    for (int jj = 0; jj < 4; ++jj) {
        int v = t + NT * jj;
        float4 X = x4[rowBase + v];
        float4 M = mean4[v];
        unsigned k0 = kk[4*jj+0], k1 = kk[4*jj+1], k2 = kk[4*jj+2], k3 = kk[4*jj+3];
        vfloat4 o;
        o.x = (k0 <= keyHi) ? ((k0 >= keyLo) ? X.x - M.x : -M.x) : 0.0f;
        o.y = (k1 <= keyHi) ? ((k1 >= keyLo) ? X.y - M.y : -M.y) : 0.0f;
        o.z = (k2 <= keyHi) ? ((k2 >= keyLo) ? X.z - M.z : -M.z) : 0.0f;
        o.w = (k3 <= keyHi) ? ((k3 >= keyLo) ? X.w - M.w : -M.w) : 0.0f;
        __builtin_nontemporal_store(o, reinterpret_cast<vfloat4*>(&out4[rowBase + v]));
    }
}

extern "C" void kernel_launch(void* const* d_in, const int* in_sizes, int n_in,
                              void* d_out, int out_size, void* d_ws, size_t ws_size,
                              hipStream_t stream) {
    const float* x  = (const float*)d_in[0];
    const float* aa = (const float*)d_in[1];
    float* out = (float*)d_out;

    const int F   = in_sizes[1];          // 4096
    const int B   = in_sizes[0] / F;      // 8192
    const int F4v = F / 4;
    const int rankLo = (int)((double)F * 0.05) + TOP_IG;   // 211
    const int rankHi = TOP_IG;                              // 7

    int nChunks = 256;
    while (nChunks > 1 &&
           ((size_t)nChunks + 2) * (size_t)F * sizeof(float) > ws_size)
        nChunks >>= 1;
    if (nChunks > B) nChunks = B;

    float* part   = (float*)d_ws;
    float* mean   = part + (size_t)nChunks * F;
    float* factor = mean + F;
    int rpc = (B + nChunks - 1) / nChunks;

    dim3 g1((F4v + NT1 - 1) / NT1, nChunks);
    k_colsum_partial<<<g1, NT1, 0, stream>>>((const float4*)x, (float4*)part, B, F4v, rpc);

    k_finalize_stats<<<dim3((F4v + 63) / 64), NT, 0, stream>>>(
        (const float4*)part, (const float4*)aa, (float4*)mean, (float4*)factor, B, F4v, nChunks);

    k_select_apply<<<dim3(B), NT, 0, stream>>>(
        (const float4*)x, (const float4*)factor, (const float4*)mean, (float4*)out,
        rankHi, rankLo);
}

// Round 12
// 84.286 us; speedup vs baseline: 9.0680x; 1.3013x over previous
//
#include <hip/hip_runtime.h>
#include <cstdint>
#include <cmath>

#define DENSITY   0.05f
#define TOP_IG    7
#define NT        256
#define NT1       64
#define FEAT      4096
#define FEAT4     1024
#define NBINS     1024     // 10-bit pass-1 digit: key>>22 (sign+exp+1 mantissa bit)
#define CAPF      32       // finalist cap (typ 1-3)

typedef float vfloat4 __attribute__((ext_vector_type(4)));

// monotonic float -> uint order key (ascending float == ascending key)
__device__ __forceinline__ unsigned fkey(float f) {
    unsigned u = __float_as_uint(f);
    return (u & 0x80000000u) ? ~u : (u | 0x80000000u);
}
__device__ __forceinline__ float fkey_inv(unsigned k) {
    unsigned u = (k & 0x80000000u) ? (k & 0x7fffffffu) : ~k;
    return __uint_as_float(u);
}

// ---------------- kernel 1: chunked column partial sums (frozen) ----------------
__global__ __launch_bounds__(NT1)
void k_colsum_partial(const float4* __restrict__ x4, float4* __restrict__ part4,
                      int B, int F4v, int rowsPerChunk) {
    int cg = blockIdx.x * NT1 + threadIdx.x;
    if (cg >= F4v) return;
    int r0 = blockIdx.y * rowsPerChunk;
    int r1 = r0 + rowsPerChunk; if (r1 > B) r1 = B;
    float4 s0 = make_float4(0.f,0.f,0.f,0.f), s1 = s0, s2 = s0, s3 = s0;
    int r = r0;
    for (; r + 4 <= r1; r += 4) {
        float4 a = x4[(size_t)(r+0) * F4v + cg];
        float4 b = x4[(size_t)(r+1) * F4v + cg];
        float4 c = x4[(size_t)(r+2) * F4v + cg];
        float4 d = x4[(size_t)(r+3) * F4v + cg];
        s0.x += a.x; s0.y += a.y; s0.z += a.z; s0.w += a.w;
        s1.x += b.x; s1.y += b.y; s1.z += b.z; s1.w += b.w;
        s2.x += c.x; s2.y += c.y; s2.z += c.z; s2.w += c.w;
        s3.x += d.x; s3.y += d.y; s3.z += d.z; s3.w += d.w;
    }
    for (; r < r1; ++r) {
        float4 a = x4[(size_t)r * F4v + cg];
        s0.x += a.x; s0.y += a.y; s0.z += a.z; s0.w += a.w;
    }
    float4 s = make_float4(s0.x+s1.x+s2.x+s3.x, s0.y+s1.y+s2.y+s3.y,
                           s0.z+s1.z+s2.z+s3.z, s0.w+s1.w+s2.w+s3.w);
    part4[(size_t)blockIdx.y * F4v + cg] = s;
}

// ------- kernel 2: reduce partials -> mean; factor + invFactor (re-parallelized) -------
// grid = F4v/16 blocks; block = [16 colgroups][16 strands]; strand s sums chunks s::16.
__global__ __launch_bounds__(NT)
void k_finalize_stats(const float4* __restrict__ part4, const float4* __restrict__ aa4,
                      float4* __restrict__ mean4, float4* __restrict__ factor4,
                      float4* __restrict__ invf4, int B, int F4v, int nChunks) {
    __shared__ float4 red[16][17];
    const int c  = threadIdx.x >> 4;
    const int s  = threadIdx.x & 15;
    const int cg = blockIdx.x * 16 + c;
    float4 acc = make_float4(0.f, 0.f, 0.f, 0.f);
    if (cg < F4v) {
        for (int ch = s; ch < nChunks; ch += 16) {
            float4 v = part4[(size_t)ch * F4v + cg];
            acc.x += v.x; acc.y += v.y; acc.z += v.z; acc.w += v.w;
        }
    }
    red[c][s] = acc;
    __syncthreads();
    if (s == 0 && cg < F4v) {
        float4 t = red[c][0];
        #pragma unroll
        for (int i = 1; i < 16; ++i) {
            float4 v = red[c][i];
            t.x += v.x; t.y += v.y; t.z += v.z; t.w += v.w;
        }
        float invB = 1.0f / (float)B;
        mean4[cg] = make_float4(t.x * invB, t.y * invB, t.z * invB, t.w * invB);
        float4 a = aa4[cg];
        float fx = (float)exp((double)(DENSITY - a.x));
        float fy = (float)exp((double)(DENSITY - a.y));
        float fz = (float)exp((double)(DENSITY - a.z));
        float fw = (float)exp((double)(DENSITY - a.w));
        factor4[cg] = make_float4(fx, fy, fz, fw);
        invf4[cg]   = make_float4(1.0f / fx, 1.0f / fy, 1.0f / fz, 1.0f / fw);
    }
}

// wave inclusive scan + total of per-lane value
__device__ __forceinline__ void wscan(unsigned T, int lane, unsigned& incl, unsigned& tot) {
    unsigned P = T;
    #pragma unroll
    for (int off = 1; off < 64; off <<= 1) {
        unsigned n = __shfl_up(P, off, 64);
        if (lane >= off) P += n;
    }
    incl = P;
    tot = __shfl(P, 63, 64);
}

// find rank rr_in in a 256-bin histogram (lane owns 4 bins via uint4) — wave-level
__device__ __forceinline__ void select256(const unsigned* h, int lane,
                                          unsigned rr_in, unsigned& sub, unsigned& rr) {
    uint4 c = *reinterpret_cast<const uint4*>(&h[lane << 2]);
    unsigned T = c.x + c.y + c.z + c.w;
    unsigned incl, tot; wscan(T, lane, incl, tot);
    unsigned above = tot - incl;
    bool hit = (above < rr_in) && (rr_in <= above + T);
    unsigned long long mk = __ballot(hit);
    int src = __ffsll(mk) - 1;
    unsigned aS = __shfl(above, src, 64);
    unsigned c0 = __shfl(c.x, src, 64), c1 = __shfl(c.y, src, 64);
    unsigned c2 = __shfl(c.z, src, 64), c3 = __shfl(c.w, src, 64);
    unsigned a3 = aS, a2 = a3 + c3, a1 = a2 + c2, a0 = a1 + c1;
    unsigned b, a;
    if      (a3 < rr_in && rr_in <= a3 + c3) { b = 3u; a = a3; }
    else if (a2 < rr_in && rr_in <= a2 + c2) { b = 2u; a = a2; }
    else if (a1 < rr_in && rr_in <= a1 + c1) { b = 1u; a = a1; }
    else                                     { b = 0u; a = a0; }
    sub = ((unsigned)src << 2) | b;
    rr  = rr_in - a;
}

// duplicate-aware rank resolve among finalists (wave-level, redundant per wave)
__device__ __forceinline__ unsigned resolve_fin(const unsigned* fin, unsigned K,
                                                unsigned rr, int lane) {
    unsigned myk = fin[lane < (int)K ? lane : 0];
    unsigned gt = 0, eq = 0;
    for (unsigned i = 0; i < K; ++i) {
        unsigned v = fin[i];                 // LDS broadcast
        gt += (v > myk) ? 1u : 0u;
        eq += (v == myk) ? 1u : 0u;
    }
    bool hit = (lane < (int)K) && (gt < rr) && (rr <= gt + eq);
    unsigned long long mk = __ballot(hit);
    if (mk == 0ull) return fin[0];           // cap-overflow fallback
    int src = __ffsll(mk) - 1;
    return __shfl(myk, src, 64);
}

// ------------- kernel 3: block-per-row dual select; G reconstructs x from keys -------------
__global__ __launch_bounds__(NT)
void k_select_apply(const float4* __restrict__ x4, const float4* __restrict__ factor4,
                    const float4* __restrict__ invf4, const float4* __restrict__ mean4,
                    float4* __restrict__ out4, int rankHi, int rankLo) {
    __shared__ __align__(16) unsigned hist[NBINS];   // 4 KB
    __shared__ __align__(16) unsigned h8[2][256];    // 2 KB
    __shared__ unsigned fin[2][CAPF];                // 256 B
    __shared__ unsigned fcnt[2];
    __shared__ unsigned smax[4];

    const int t    = threadIdx.x;
    const int wid  = t >> 6;
    const int lane = t & 63;
    const size_t rowBase = (size_t)blockIdx.x * FEAT4;

    // ---- zero ----
    *reinterpret_cast<uint4*>(&hist[4 * t]) = make_uint4(0u,0u,0u,0u);
    h8[0][t] = 0u; h8[1][t] = 0u;
    if (t < 2) fcnt[t] = 0u;
    __syncthreads();                                   // B1

    // ---- phase A: keygen (keys stay in VGPRs) + 10-bit histogram + wave max ----
    unsigned kk[16];
    unsigned wm = 0u;
    #pragma unroll
    for (int jj = 0; jj < 4; ++jj) {
        int v = t + NT * jj;
        float4 X  = x4[rowBase + v];
        float4 Fa = factor4[v];
        unsigned k0 = fkey(X.x * Fa.x), k1 = fkey(X.y * Fa.y);
        unsigned k2 = fkey(X.z * Fa.z), k3 = fkey(X.w * Fa.w);
        kk[4*jj+0] = k0; kk[4*jj+1] = k1; kk[4*jj+2] = k2; kk[4*jj+3] = k3;
        wm = max(max(max(wm, k0), max(k1, k2)), k3);
        atomicAdd(&hist[k0 >> 22], 1u);
        atomicAdd(&hist[k1 >> 22], 1u);
        atomicAdd(&hist[k2 >> 22], 1u);
        atomicAdd(&hist[k3 >> 22], 1u);
    }
    #pragma unroll
    for (int off = 32; off > 0; off >>= 1)
        wm = max(wm, (unsigned)__shfl_xor(wm, off, 64));
    if (lane == 0) smax[wid] = wm;
    __syncthreads();                                   // B2

    // ---- phase B: windowed suffix scan from the top bin (redundant per wave) ----
    unsigned bin0 = 0, rr0 = (unsigned)rankHi;         // rank 7 (top_ig)
    unsigned bin1 = 0, rr1 = (unsigned)rankLo;         // rank 211 (kth)
    {
        unsigned bm = max(max(smax[0], smax[1]), max(smax[2], smax[3]));
        int wstart = (int)(bm >> 22);
        bool f0 = false, f1 = false;
        unsigned base = 0u;
        while (!(f0 && f1)) {
            int b = wstart - lane;
            unsigned c = (b >= 0) ? hist[b] : 0u;
            unsigned incl, tot; wscan(c, lane, incl, tot);
            unsigned above = base + incl - c;
            unsigned cum   = base + incl;
            if (!f0) {
                bool hit = (above < rr0) && (rr0 <= cum);
                unsigned long long mk = __ballot(hit);
                if (mk) { int s = __ffsll(mk) - 1; bin0 = (unsigned)(wstart - s);
                          rr0 -= __shfl(above, s, 64); f0 = true; }
            }
            if (!f1) {
                bool hit = (above < rr1) && (rr1 <= cum);
                unsigned long long mk = __ballot(hit);
                if (mk) { int s = __ffsll(mk) - 1; bin1 = (unsigned)(wstart - s);
                          rr1 -= __shfl(above, s, 64); f1 = true; }
            }
            base += tot;
            wstart -= 64;
        }
    }

    // ---- phase C: 8-bit sub-histograms for both target bins ----
    #pragma unroll
    for (int j = 0; j < 16; ++j) {
        unsigned k = kk[j];
        unsigned d = k >> 22;
        if (d == bin1) atomicAdd(&h8[1][(k >> 14) & 255u], 1u);
        if (d == bin0) atomicAdd(&h8[0][(k >> 14) & 255u], 1u);
    }
    __syncthreads();                                   // B3

    // ---- phase D: sub-digit select, both targets, redundant per wave ----
    unsigned sub0, rrf0; select256(&h8[0][0], lane, rr0, sub0, rrf0);
    unsigned sub1, rrf1; select256(&h8[1][0], lane, rr1, sub1, rrf1);

    // ---- phase E: finalist gather by re-scanning register keys (18-bit prefix) ----
    {
        unsigned pre0 = (bin0 << 8) | sub0;
        unsigned pre1 = (bin1 << 8) | sub1;
        #pragma unroll
        for (int j = 0; j < 16; ++j) {
            unsigned k = kk[j];
            unsigned p = k >> 14;
            if (p == pre1) { unsigned f = atomicAdd(&fcnt[1], 1u); if (f < CAPF) fin[1][f] = k; }
            if (p == pre0) { unsigned f = atomicAdd(&fcnt[0], 1u); if (f < CAPF) fin[0][f] = k; }
        }
    }
    __syncthreads();                                   // B4

    // ---- phase F: exact rank among finalists, redundant per wave ----
    unsigned K0 = fcnt[0]; if (K0 > CAPF) K0 = CAPF;
    unsigned K1 = fcnt[1]; if (K1 > CAPF) K1 = CAPF;
    const unsigned keyHi = resolve_fin(&fin[0][0], K0, rrf0, lane);
    const unsigned keyLo = resolve_fin(&fin[1][0], K1, rrf1, lane);

    // ---- phase G: reconstruct x from keys (NO x re-read), apply masks, nt-store ----
    #pragma unroll
    for (int jj = 0; jj < 4; ++jj) {
        int v = t + NT * jj;
        float4 Fi = invf4[v];
        float4 M  = mean4[v];
        unsigned k0 = kk[4*jj+0], k1 = kk[4*jj+1], k2 = kk[4*jj+2], k3 = kk[4*jj+3];
        float xp0 = fkey_inv(k0), xp1 = fkey_inv(k1);
        float xp2 = fkey_inv(k2), xp3 = fkey_inv(k3);
        vfloat4 o;
        o.x = (k0 <= keyHi) ? ((k0 >= keyLo) ? __builtin_fmaf(xp0, Fi.x, -M.x) : -M.x) : 0.0f;
        o.y = (k1 <= keyHi) ? ((k1 >= keyLo) ? __builtin_fmaf(xp1, Fi.y, -M.y) : -M.y) : 0.0f;
        o.z = (k2 <= keyHi) ? ((k2 >= keyLo) ? __builtin_fmaf(xp2, Fi.z, -M.z) : -M.z) : 0.0f;
        o.w = (k3 <= keyHi) ? ((k3 >= keyLo) ? __builtin_fmaf(xp3, Fi.w, -M.w) : -M.w) : 0.0f;
        __builtin_nontemporal_store(o, reinterpret_cast<vfloat4*>(&out4[rowBase + v]));
    }
}

extern "C" void kernel_launch(void* const* d_in, const int* in_sizes, int n_in,
                              void* d_out, int out_size, void* d_ws, size_t ws_size,
                              hipStream_t stream) {
    const float* x  = (const float*)d_in[0];
    const float* aa = (const float*)d_in[1];
    float* out = (float*)d_out;

    const int F   = in_sizes[1];          // 4096
    const int B   = in_sizes[0] / F;      // 8192
    const int F4v = F / 4;
    const int rankLo = (int)((double)F * 0.05) + TOP_IG;   // 211
    const int rankHi = TOP_IG;                              // 7

    int nChunks = 256;
    while (nChunks > 1 &&
           ((size_t)nChunks + 3) * (size_t)F * sizeof(float) > ws_size)
        nChunks >>= 1;
    if (nChunks > B) nChunks = B;

    float* part   = (float*)d_ws;
    float* mean   = part + (size_t)nChunks * F;
    float* factor = mean + F;
    float* invf   = factor + F;
    int rpc = (B + nChunks - 1) / nChunks;

    dim3 g1((F4v + NT1 - 1) / NT1, nChunks);
    k_colsum_partial<<<g1, NT1, 0, stream>>>((const float4*)x, (float4*)part, B, F4v, rpc);

    k_finalize_stats<<<dim3((F4v + 15) / 16), NT, 0, stream>>>(
        (const float4*)part, (const float4*)aa, (float4*)mean, (float4*)factor,
        (float4*)invf, B, F4v, nChunks);

    k_select_apply<<<dim3(B), NT, 0, stream>>>(
        (const float4*)x, (const float4*)factor, (const float4*)invf, (const float4*)mean,
        (float4*)out, rankHi, rankLo);
}